// Round 1
// baseline (5577.195 us; speedup 1.0000x reference)
//
#include <hip/hip_runtime.h>
#include <hip/hip_bf16.h>
#include <math.h>

// R1: fully-fused, one workgroup per batch element (4096 blocks x 256 thr).
// All per-element tensors in LDS as bf16 (63.7 KB -> 2 blocks/CU), f32 acc.
// Zero workspace use. Compute-bound fp32-VALU baseline; MFMA comes next round.

#define DIMX 256
#define LSEQ 17
#define DI   512
#define DS4  4
#define DTR  16
#define HIDX 1024

typedef unsigned short u16;

__device__ __forceinline__ float b2f(u16 u) {
    union { unsigned int i; float f; } x; x.i = ((unsigned int)u) << 16; return x.f;
}
__device__ __forceinline__ u16 f2b(float f) {
    union { float f; unsigned int i; } x; x.f = f;
    unsigned int r = x.i + 0x7FFFu + ((x.i >> 16) & 1u);
    return (u16)(r >> 16);
}
__device__ __forceinline__ float gelu_t(float x) {
    const float c = 0.7978845608028654f;
    float t = tanhf(c * (x + 0.044715f * x * x * x));
    return 0.5f * x * (1.0f + t);
}
__device__ __forceinline__ float siluf(float x) { return x / (1.0f + expf(-x)); }
__device__ __forceinline__ float softplusf(float x) { return (x > 20.0f) ? x : log1pf(expf(x)); }

__device__ const int   ADJ_MASK[17] = {0x93,0x7,0xE,0xC,0x31,0x70,0x60,0x181,0x4B80,
                                       0x700,0x600,0x1900,0x3800,0x3000,0xC100,0x1C000,0x18000};
__device__ const float DEG[17]  = {4,3,3,2,3,3,2,3,5,3,2,3,3,2,3,3,2};
__device__ const int   HOPA[17]   = {0,1,4,7,2,5,8,3,6,9,11,14,10,12,15,13,16};
__device__ const int   GRAPHA[17] = {0,1,4,7,2,5,8,3,6,9,12,10,13,15,11,14,16};
__device__ const int   BPEI[17]   = {0,1,2,0,1,2,0,1,2,0,3,4,0,3,4,3,4};

struct Params {
    const float *x, *gcn_ln_g, *gcn_ln_b, *gcn_w1, *gcn_b1, *gcn_w2, *gcn_b2,
                *bp_embed, *ssm_ln_g, *ssm_ln_b, *in_proj_w, *conv_w, *conv_b,
                *x_proj_w, *dt_proj_w, *dt_proj_b, *A_log, *Dp, *out_proj_w,
                *ln1_g, *ln1_b, *qkv_w, *attn_proj_w, *attn_proj_b,
                *ln2_g, *ln2_b, *mlp_w1, *mlp_b1, *mlp_w2, *mlp_b2;
    float *out;
};

// LayerNorm over rows of [17][256] bf16 LDS. 4 waves, each wave owns rows w, w+4, ...
__device__ __forceinline__ void ln17(const u16* __restrict__ src, u16* __restrict__ dst,
                                     const float* __restrict__ g, const float* __restrict__ b) {
    const int wv = threadIdx.x >> 6, lane = threadIdx.x & 63;
    for (int l = wv; l < LSEQ; l += 4) {
        float v[4], s = 0.f, s2 = 0.f;
        #pragma unroll
        for (int j = 0; j < 4; ++j) {
            v[j] = b2f(src[l * 256 + lane + 64 * j]);
            s += v[j]; s2 += v[j] * v[j];
        }
        #pragma unroll
        for (int m = 1; m < 64; m <<= 1) {
            s  += __shfl_xor(s, m, 64);
            s2 += __shfl_xor(s2, m, 64);
        }
        float mean = s * (1.0f / 256.0f);
        float var  = s2 * (1.0f / 256.0f) - mean * mean;
        float rstd = rsqrtf(var + 1e-5f);
        #pragma unroll
        for (int j = 0; j < 4; ++j) {
            int d = lane + 64 * j;
            dst[l * 256 + d] = f2b((v[j] - mean) * rstd * g[d] + b[d]);
        }
    }
}

// dst[i][d] = sum_j Ah[i][j] * src[j][d], width = 256 or 512 (bf16 LDS)
__device__ __forceinline__ void gconv(const float* __restrict__ Ah,
                                      const u16* __restrict__ src, u16* __restrict__ dst, int width) {
    for (int d = threadIdx.x; d < width; d += 256) {
        float col[17];
        #pragma unroll
        for (int j = 0; j < 17; ++j) col[j] = b2f(src[j * width + d]);
        #pragma unroll
        for (int i = 0; i < 17; ++i) {
            float s = 0.f;
            #pragma unroll
            for (int j = 0; j < 17; ++j) s += Ah[i * 17 + j] * col[j];
            dst[i * width + d] = f2b(s);
        }
    }
}

// out[17][N] = epi(in[17][K] @ W + bias). Thread t owns cols {coff + t + 256*c}.
// Input rows are LDS-broadcast (all lanes same address); weights coalesced from global.
template <int K, int NCOL, class Epi>
__device__ __forceinline__ void gemm17(const u16* __restrict__ in, int ldin,
                                       const float* __restrict__ Wg, int ldw, int coff,
                                       const float* __restrict__ bias,
                                       u16* outl, float* outg, int ldo, int ooff, Epi epi) {
    const int t = threadIdx.x;
    float acc[17 * NCOL];
    #pragma unroll
    for (int i = 0; i < 17 * NCOL; ++i) acc[i] = 0.f;

    for (int k0 = 0; k0 < K; k0 += 4) {
        float w[4 * NCOL];
        #pragma unroll
        for (int kk = 0; kk < 4; ++kk)
            #pragma unroll
            for (int c = 0; c < NCOL; ++c)
                w[kk * NCOL + c] = Wg[(k0 + kk) * ldw + coff + t + 256 * c];
        #pragma unroll
        for (int l = 0; l < 17; ++l) {
            ushort4 u = *(const ushort4*)(in + l * ldin + k0);
            float a0 = b2f(u.x), a1 = b2f(u.y), a2 = b2f(u.z), a3 = b2f(u.w);
            #pragma unroll
            for (int c = 0; c < NCOL; ++c) {
                float s = acc[l * NCOL + c];
                s += a0 * w[0 * NCOL + c];
                s += a1 * w[1 * NCOL + c];
                s += a2 * w[2 * NCOL + c];
                s += a3 * w[3 * NCOL + c];
                acc[l * NCOL + c] = s;
            }
        }
    }
    float bv[NCOL];
    #pragma unroll
    for (int c = 0; c < NCOL; ++c) bv[c] = bias ? bias[coff + t + 256 * c] : 0.f;
    #pragma unroll
    for (int l = 0; l < 17; ++l)
        #pragma unroll
        for (int c = 0; c < NCOL; ++c) {
            float v = epi(l, c, coff + t + 256 * c, acc[l * NCOL + c] + bv[c]);
            int o = l * ldo + ooff + t + 256 * c;
            if (outl) outl[o] = f2b(v);
            else      outg[o] = v;
        }
}

__global__ __launch_bounds__(256, 2) void fused_block(Params P) {
    __shared__ u16 R [LSEQ * 256];   // residual (x_a, then x_b)
    __shared__ u16 T0[LSEQ * 256];
    __shared__ u16 T1[LSEQ * 256];
    __shared__ u16 S [LSEQ * 1024];  // S0 = S (17x512), S1 = S + 17*512; also [17][1024] for MLP hidden
    __shared__ float Dbl[LSEQ * 24]; // x_proj output (dt-rank | B | C)
    __shared__ float Ah[289];

    const int tid = threadIdx.x;
    const int b = blockIdx.x;
    const float* __restrict__ xg = P.x + (size_t)b * (LSEQ * 256);

    // load x -> R (bf16), build A_HAT
    for (int i = tid; i < LSEQ * 256; i += 256) R[i] = f2b(xg[i]);
    for (int i = tid; i < 289; i += 256) {
        int r = i / 17, c = i - r * 17;
        Ah[i] = ((ADJ_MASK[r] >> c) & 1) ? rsqrtf(DEG[r] * DEG[c]) : 0.f;
    }
    __syncthreads();

    auto idepi = [] (int, int, int, float v) { return v; };

    // ---------------- GCN ----------------
    ln17(R, T0, P.gcn_ln_g, P.gcn_ln_b);
    __syncthreads();
    gconv(Ah, T0, T1, 256);
    __syncthreads();
    gemm17<256, 2>(T1, 256, P.gcn_w1, 512, 0, P.gcn_b1, S, nullptr, 512, 0,
                   [] (int, int, int, float v) { return gelu_t(v); });
    __syncthreads();
    gconv(Ah, S, S + LSEQ * 512, 512);
    __syncthreads();
    gemm17<512, 1>(S + LSEQ * 512, 512, P.gcn_w2, 256, 0, P.gcn_b2, T0, nullptr, 256, 0, idepi);
    __syncthreads();
    for (int i = tid; i < LSEQ * 256; i += 256) R[i] = f2b(b2f(R[i]) + b2f(T0[i]));  // x_a
    __syncthreads();

    // ---------------- Mamba ----------------
    for (int i = tid; i < LSEQ * 256; i += 256) {
        int l = i >> 8, d = i & 255;
        T0[i] = f2b(b2f(R[HOPA[l] * 256 + d]) + P.bp_embed[BPEI[l] * 256 + d]);
    }
    __syncthreads();
    ln17(T0, T1, P.ssm_ln_g, P.ssm_ln_b);
    __syncthreads();
    // in_proj: xm half with conv+silu, z half plain
    gemm17<256, 2>(T1, 256, P.in_proj_w, 1024, 0, nullptr, S, nullptr, 512, 0,
                   [&] (int, int, int col, float v) { return siluf(v * P.conv_w[col] + P.conv_b[col]); });
    gemm17<256, 2>(T1, 256, P.in_proj_w, 1024, 512, nullptr, S + LSEQ * 512, nullptr, 512, 0, idepi);
    __syncthreads();
    // x_proj: Dbl[17][24] = xm @ x_proj_w
    for (int idx = tid; idx < LSEQ * 24; idx += 256) {
        int t = idx / 24, c = idx - t * 24;
        float s = 0.f;
        for (int k = 0; k < 512; ++k) s += b2f(S[t * 512 + k]) * P.x_proj_w[k * 24 + c];
        Dbl[t * 24 + c] = s;
    }
    __syncthreads();
    // selective scan: thread owns channels d = tid and tid+256
    #pragma unroll
    for (int rep = 0; rep < 2; ++rep) {
        int d = tid + rep * 256;
        float wdt[16];
        #pragma unroll
        for (int r = 0; r < 16; ++r) wdt[r] = P.dt_proj_w[r * 512 + d];
        float dtb = P.dt_proj_b[d];
        float Ar[4];
        #pragma unroll
        for (int s = 0; s < 4; ++s) Ar[s] = -expf(P.A_log[d * 4 + s]);
        float Dpd = P.Dp[d];
        float h0 = 0.f, h1 = 0.f, h2 = 0.f, h3 = 0.f;
        for (int t = 0; t < LSEQ; ++t) {
            float a = dtb;
            #pragma unroll
            for (int r = 0; r < 16; ++r) a += Dbl[t * 24 + r] * wdt[r];
            float dt = softplusf(a);
            float xm = b2f(S[t * 512 + d]);
            float dtxm = dt * xm;
            float B0 = Dbl[t * 24 + 16], B1 = Dbl[t * 24 + 17], B2 = Dbl[t * 24 + 18], B3 = Dbl[t * 24 + 19];
            float C0 = Dbl[t * 24 + 20], C1 = Dbl[t * 24 + 21], C2 = Dbl[t * 24 + 22], C3 = Dbl[t * 24 + 23];
            h0 = expf(dt * Ar[0]) * h0 + dtxm * B0;
            h1 = expf(dt * Ar[1]) * h1 + dtxm * B1;
            h2 = expf(dt * Ar[2]) * h2 + dtxm * B2;
            h3 = expf(dt * Ar[3]) * h3 + dtxm * B3;
            float y = h0 * C0 + h1 * C1 + h2 * C2 + h3 * C3;
            y += Dpd * xm;
            y *= siluf(b2f(S[LSEQ * 512 + t * 512 + d]));  // gate with z
            S[t * 512 + d] = f2b(y);                        // overwrite xm with y
        }
    }
    __syncthreads();
    gemm17<512, 1>(S, 512, P.out_proj_w, 256, 0, nullptr, T0, nullptr, 256, 0, idepi);
    __syncthreads();
    // x_b = 2*x_a + scatter(mamba_out)
    for (int i = tid; i < LSEQ * 256; i += 256) {
        int l = i >> 8, d = i & 255;
        R[i] = f2b(2.0f * b2f(R[i]) + b2f(T0[GRAPHA[l] * 256 + d]));
    }
    __syncthreads();

    // ---------------- Attention ----------------
    ln17(R, T0, P.ln1_g, P.ln1_b);
    __syncthreads();
    gemm17<256, 1>(T0, 256, P.qkv_w, 768, 0,   nullptr, T1, nullptr, 256, 0,   idepi); // Q
    gemm17<256, 1>(T0, 256, P.qkv_w, 768, 256, nullptr, S,  nullptr, 512, 0,   idepi); // K
    gemm17<256, 1>(T0, 256, P.qkv_w, 768, 512, nullptr, S,  nullptr, 512, 256, idepi); // V
    __syncthreads();
    {
        const int h = tid >> 5, p = tid & 31;
        u16* SC = S + LSEQ * 512;
        for (int idx = p; idx < 289; idx += 32) {
            int i = idx / 17, j = idx - i * 17;
            float s = 0.f;
            #pragma unroll
            for (int d2 = 0; d2 < 32; ++d2)
                s += b2f(T1[i * 256 + h * 32 + d2]) * b2f(S[j * 512 + h * 32 + d2]);
            SC[(h * 17 + i) * 17 + j] = f2b(s * 0.17677669529663687f);
        }
    }
    __syncthreads();
    if (tid < 136) {
        u16* row = S + LSEQ * 512 + tid * 17;
        float e[17], mx = -3.0e38f, sum = 0.f;
        #pragma unroll
        for (int j = 0; j < 17; ++j) mx = fmaxf(mx, b2f(row[j]));
        #pragma unroll
        for (int j = 0; j < 17; ++j) { e[j] = expf(b2f(row[j]) - mx); sum += e[j]; }
        float inv = 1.0f / sum;
        #pragma unroll
        for (int j = 0; j < 17; ++j) row[j] = f2b(e[j] * inv);
    }
    __syncthreads();
    {
        const int h = tid >> 5, dd = tid & 31;
        const u16* SC = S + LSEQ * 512;
        for (int i = 0; i < 17; ++i) {
            float s = 0.f;
            #pragma unroll
            for (int j = 0; j < 17; ++j)
                s += b2f(SC[(h * 17 + i) * 17 + j]) * b2f(S[j * 512 + 256 + h * 32 + dd]);
            T0[i * 256 + h * 32 + dd] = f2b(s);
        }
    }
    __syncthreads();
    // x1 = x_b + attn_proj(o)
    gemm17<256, 1>(T0, 256, P.attn_proj_w, 256, 0, P.attn_proj_b, T1, nullptr, 256, 0,
                   [&] (int l, int, int col, float v) { return v + b2f(R[l * 256 + col]); });
    __syncthreads();

    // ---------------- MLP + final ----------------
    ln17(T1, T0, P.ln2_g, P.ln2_b);
    __syncthreads();
    gemm17<256, 4>(T0, 256, P.mlp_w1, 1024, 0, P.mlp_b1, S, nullptr, 1024, 0,
                   [] (int, int, int, float v) { return gelu_t(v); });
    __syncthreads();
    // out = x1 + mlp2(h) + x_b   (written straight to global)
    gemm17<1024, 1>(S, 1024, P.mlp_w2, 256, 0, P.mlp_b2,
                    nullptr, P.out + (size_t)b * (LSEQ * 256), 256, 0,
                    [&] (int l, int, int col, float v) {
                        return v + b2f(T1[l * 256 + col]) + b2f(R[l * 256 + col]);
                    });
}

extern "C" void kernel_launch(void* const* d_in, const int* in_sizes, int n_in,
                              void* d_out, int out_size, void* d_ws, size_t ws_size,
                              hipStream_t stream) {
    (void)in_sizes; (void)n_in; (void)d_ws; (void)ws_size; (void)out_size;
    Params P;
    P.x           = (const float*)d_in[0];
    P.gcn_ln_g    = (const float*)d_in[1];
    P.gcn_ln_b    = (const float*)d_in[2];
    P.gcn_w1      = (const float*)d_in[3];
    P.gcn_b1      = (const float*)d_in[4];
    P.gcn_w2      = (const float*)d_in[5];
    P.gcn_b2      = (const float*)d_in[6];
    P.bp_embed    = (const float*)d_in[7];
    P.ssm_ln_g    = (const float*)d_in[8];
    P.ssm_ln_b    = (const float*)d_in[9];
    P.in_proj_w   = (const float*)d_in[10];
    P.conv_w      = (const float*)d_in[11];
    P.conv_b      = (const float*)d_in[12];
    P.x_proj_w    = (const float*)d_in[13];
    P.dt_proj_w   = (const float*)d_in[14];
    P.dt_proj_b   = (const float*)d_in[15];
    P.A_log       = (const float*)d_in[16];
    P.Dp          = (const float*)d_in[17];
    P.out_proj_w  = (const float*)d_in[18];
    P.ln1_g       = (const float*)d_in[19];
    P.ln1_b       = (const float*)d_in[20];
    P.qkv_w       = (const float*)d_in[21];
    P.attn_proj_w = (const float*)d_in[22];
    P.attn_proj_b = (const float*)d_in[23];
    P.ln2_g       = (const float*)d_in[24];
    P.ln2_b       = (const float*)d_in[25];
    P.mlp_w1      = (const float*)d_in[26];
    P.mlp_b1      = (const float*)d_in[27];
    P.mlp_w2      = (const float*)d_in[28];
    P.mlp_b2      = (const float*)d_in[29];
    P.out         = (float*)d_out;
    hipLaunchKernelGGL(fused_block, dim3(4096), dim3(256), 0, stream, P);
}

// Round 2
// 2656.176 us; speedup vs baseline: 2.0997x; 2.0997x over previous
//
#include <hip/hip_runtime.h>
#include <hip/hip_bf16.h>
#include <math.h>

// R2: fused one-block-per-element + MFMA GEMMs.
// - Weights prepacked (fp32 -> bf16 B-fragments) into d_ws each launch.
// - M=17 padded to 2 M-tiles of 16 (tile1 = row 16 only).
// - Residual R kept fp32 in LDS; z-gate fused into epilogue; in-place gconv.
// LDS = 60.7 KB -> 2 blocks/CU.

#define LSEQ 17
#define RS 260   // R row stride (f32)
#define TS 264   // T0/T1 row stride (u16)
#define SS 520   // S0 row stride (u16)

typedef unsigned short u16;
typedef __attribute__((ext_vector_type(8))) short short8;
typedef __attribute__((ext_vector_type(4))) float f32x4;

__device__ __forceinline__ float b2f(u16 u) {
    union { unsigned int i; float f; } x; x.i = ((unsigned int)u) << 16; return x.f;
}
__device__ __forceinline__ u16 f2b(float f) {
    union { float f; unsigned int i; } x; x.f = f;
    unsigned int r = x.i + 0x7FFFu + ((x.i >> 16) & 1u);
    return (u16)(r >> 16);
}
__device__ __forceinline__ float gelu_t(float x) {
    const float c = 0.7978845608028654f;
    float t = tanhf(c * (x + 0.044715f * x * x * x));
    return 0.5f * x * (1.0f + t);
}
__device__ __forceinline__ float siluf(float x) { return x / (1.0f + expf(-x)); }
__device__ __forceinline__ float softplusf(float x) { return (x > 20.0f) ? x : log1pf(expf(x)); }

__device__ const int   ADJ_MASK[17] = {0x93,0x7,0xE,0xC,0x31,0x70,0x60,0x181,0x4B80,
                                       0x700,0x600,0x1900,0x3800,0x3000,0xC100,0x1C000,0x18000};
__device__ const float DEG[17]    = {4,3,3,2,3,3,2,3,5,3,2,3,3,2,3,3,2};
__device__ const int   HOPA[17]   = {0,1,4,7,2,5,8,3,6,9,11,14,10,12,15,13,16};
__device__ const int   GRAPHA[17] = {0,1,4,7,2,5,8,3,6,9,12,10,13,15,11,14,16};
__device__ const int   BPEI[17]   = {0,1,2,0,1,2,0,1,2,0,3,4,0,3,4,3,4};

// ws fragment offsets (elements, bf16)
#define OFF_GCN_W1   0
#define OFF_GCN_W2   131072
#define OFF_INPROJ   262144
#define OFF_OUTPROJ  524288
#define OFF_QKV      655360
#define OFF_ATTNPROJ 851968
#define OFF_MLP_W1   917504
#define OFF_MLP_W2   1179648
#define OFF_XPROJ    1441792
#define WS_ELEMS     1458176

struct Params {
    const float *x, *gcn_ln_g, *gcn_ln_b, *gcn_w1, *gcn_b1, *gcn_w2, *gcn_b2,
                *bp_embed, *ssm_ln_g, *ssm_ln_b, *in_proj_w, *conv_w, *conv_b,
                *x_proj_w, *dt_proj_w, *dt_proj_b, *A_log, *Dp, *out_proj_w,
                *ln1_g, *ln1_b, *qkv_w, *attn_proj_w, *attn_proj_b,
                *ln2_g, *ln2_b, *mlp_w1, *mlp_b1, *mlp_w2, *mlp_b2;
    const u16* wws;
    float* out;
};

// ---------------- weight prepack: fp32 [K][N] -> bf16 B-fragments ----------------
// frag layout: ws[off + ((kc*NT + nt)*64 + lane)*8 + j] = bf16(W[kc*32 + (lane>>4)*8 + j][nt*16 + (lane&15)])
__global__ __launch_bounds__(256) void prepack(Params P) {
    const int gid = blockIdx.x * 256 + threadIdx.x;
    const int cnt[9]  = {16384,16384,32768,16384,24576,8192,32768,32768,2048};
    const int Ns [9]  = {512,256,1024,256,768,256,1024,256,24};
    const int NPs[9]  = {512,256,1024,256,768,256,1024,256,32};
    const int offs[9] = {OFF_GCN_W1,OFF_GCN_W2,OFF_INPROJ,OFF_OUTPROJ,OFF_QKV,
                         OFF_ATTNPROJ,OFF_MLP_W1,OFF_MLP_W2,OFF_XPROJ};
    int e = 0, base = 0;
    while (e < 9 && gid >= base + cnt[e]) { base += cnt[e]; ++e; }
    if (e >= 9) return;
    const float* W;
    switch (e) {
        case 0: W = P.gcn_w1; break;      case 1: W = P.gcn_w2; break;
        case 2: W = P.in_proj_w; break;   case 3: W = P.out_proj_w; break;
        case 4: W = P.qkv_w; break;       case 5: W = P.attn_proj_w; break;
        case 6: W = P.mlp_w1; break;      case 7: W = P.mlp_w2; break;
        default: W = P.x_proj_w; break;
    }
    const int local = gid - base;
    const int lane = local & 63, frag = local >> 6;
    const int NT = NPs[e] >> 4;
    const int nt = frag % NT, kc = frag / NT;
    const int n = nt * 16 + (lane & 15);
    const int kbase = kc * 32 + (lane >> 4) * 8;
    u16 v[8];
    #pragma unroll
    for (int j = 0; j < 8; ++j)
        v[j] = (n < Ns[e]) ? f2b(W[(size_t)(kbase + j) * Ns[e] + n]) : (u16)0;
    u16* dst = (u16*)P.wws + offs[e] + ((size_t)frag * 64 + lane) * 8;
    *(short8*)dst = *(short8*)v;
}

// ---------------- MFMA helpers ----------------
// acc[mt][i]: M-tile mt (rows 0-15, row 16), N-tile nt0 + wv + 4*i.
template <int KT, int NT4>
__device__ __forceinline__ void mfmaAcc(f32x4 acc[2][NT4],
        const u16* __restrict__ act, int ldin,
        const u16* __restrict__ wbase, int NT, int nt0, int ntcnt, int kc0) {
    const int lane = threadIdx.x & 63, wv = threadIdx.x >> 6;
    const int m = lane & 15, quad = lane >> 4;
    for (int kc = 0; kc < KT; ++kc) {
        short8 a0 = *(const short8*)(act + m * ldin + kc * 32 + quad * 8);
        short8 a1 = {0,0,0,0,0,0,0,0};
        if (m == 0) a1 = *(const short8*)(act + 16 * ldin + kc * 32 + quad * 8);
        #pragma unroll
        for (int i = 0; i < NT4; ++i) {
            const int ntl = wv + 4 * i;
            if (ntl < ntcnt) {
                const short8 b = *(const short8*)(wbase +
                    ((size_t)((kc0 + kc) * NT + nt0 + ntl) * 64 + lane) * 8);
                acc[0][i] = __builtin_amdgcn_mfma_f32_16x16x32_bf16(a0, b, acc[0][i], 0, 0, 0);
                acc[1][i] = __builtin_amdgcn_mfma_f32_16x16x32_bf16(a1, b, acc[1][i], 0, 0, 0);
            }
        }
    }
}

// epi(row, col_rel, val): row in [0,17), col_rel relative to this call's first tile.
template <int NT4, class Epi>
__device__ __forceinline__ void mfmaStore(f32x4 acc[2][NT4], int ntcnt, Epi epi) {
    const int lane = threadIdx.x & 63, wv = threadIdx.x >> 6;
    const int col0 = lane & 15, quad = lane >> 4;
    #pragma unroll
    for (int i = 0; i < NT4; ++i) {
        const int ntl = wv + 4 * i;
        if (ntl < ntcnt) {
            const int cb = ntl * 16 + col0;
            #pragma unroll
            for (int r = 0; r < 4; ++r) epi(quad * 4 + r, cb, acc[0][i][r]);
            if (quad == 0) epi(16, cb, acc[1][i][0]);
        }
    }
}

template <int KT, int NT4, class Epi>
__device__ __forceinline__ void gemmM(const u16* act, int ldin,
        const u16* wbase, int NT, int nt0, int ntcnt, Epi epi) {
    f32x4 acc[2][NT4];
    #pragma unroll
    for (int mt = 0; mt < 2; ++mt)
        #pragma unroll
        for (int i = 0; i < NT4; ++i) acc[mt][i] = (f32x4){0.f,0.f,0.f,0.f};
    mfmaAcc<KT, NT4>(acc, act, ldin, wbase, NT, nt0, ntcnt, 0);
    mfmaStore<NT4>(acc, ntcnt, epi);
}

// ---------------- main fused kernel ----------------
__global__ __launch_bounds__(256, 2) void fused_block(Params P) {
    __shared__ __align__(16) float R [LSEQ * RS];   // residual, fp32
    __shared__ __align__(16) u16   T0[LSEQ * TS];
    __shared__ __align__(16) u16   T1[LSEQ * TS];
    __shared__ __align__(16) u16   S0[LSEQ * SS];
    __shared__ __align__(16) u16   SC[8 * 17 * 17]; // attention scores
    __shared__ float Dbl[LSEQ * 24];
    __shared__ float Ah[289];

    const int tid = threadIdx.x;
    const int lane = tid & 63, wv = tid >> 6;
    const int b = blockIdx.x;
    const float* __restrict__ xg = P.x + (size_t)b * (LSEQ * 256);
    const u16* __restrict__ ws = P.wws;

    for (int i = tid; i < LSEQ * 256; i += 256) {
        int l = i >> 8, d = i & 255;
        R[l * RS + d] = xg[i];
    }
    for (int i = tid; i < 289; i += 256) {
        int r = i / 17, c = i - r * 17;
        Ah[i] = ((ADJ_MASK[r] >> c) & 1) ? rsqrtf(DEG[r] * DEG[c]) : 0.f;
    }
    __syncthreads();

    // generic LN over 17 rows of 256
    auto ln17g = [&](auto ld, u16* dst, const float* g, const float* bb) {
        for (int l = wv; l < LSEQ; l += 4) {
            float v[4], s = 0.f, s2 = 0.f;
            #pragma unroll
            for (int j = 0; j < 4; ++j) {
                v[j] = ld(l, lane + 64 * j);
                s += v[j]; s2 += v[j] * v[j];
            }
            #pragma unroll
            for (int m = 1; m < 64; m <<= 1) {
                s  += __shfl_xor(s, m, 64);
                s2 += __shfl_xor(s2, m, 64);
            }
            float mean = s * (1.0f / 256.0f);
            float var  = s2 * (1.0f / 256.0f) - mean * mean;
            float rstd = rsqrtf(var + 1e-5f);
            #pragma unroll
            for (int j = 0; j < 4; ++j) {
                int d = lane + 64 * j;
                dst[l * TS + d] = f2b((v[j] - mean) * rstd * g[d] + bb[d]);
            }
        }
    };
    auto gconvIP = [&](u16* buf, int stride, int width) {
        for (int d = tid; d < width; d += 256) {
            float col[17];
            #pragma unroll
            for (int j = 0; j < 17; ++j) col[j] = b2f(buf[j * stride + d]);
            #pragma unroll
            for (int i = 0; i < 17; ++i) {
                float s = 0.f;
                #pragma unroll
                for (int j = 0; j < 17; ++j) s += Ah[i * 17 + j] * col[j];
                buf[i * stride + d] = f2b(s);
            }
        }
    };

    // ---------------- GCN ----------------
    ln17g([&](int l, int d) { return R[l * RS + d]; }, T0, P.gcn_ln_g, P.gcn_ln_b);
    __syncthreads();
    gconvIP(T0, TS, 256);
    __syncthreads();
    gemmM<8, 8>(T0, TS, ws + OFF_GCN_W1, 32, 0, 32,
        [&](int l, int c, float v) { S0[l * SS + c] = f2b(gelu_t(v + P.gcn_b1[c])); });
    __syncthreads();
    gconvIP(S0, SS, 512);
    __syncthreads();
    gemmM<16, 4>(S0, SS, ws + OFF_GCN_W2, 16, 0, 16,
        [&](int l, int c, float v) { R[l * RS + c] += v + P.gcn_b2[c]; });  // x_a
    __syncthreads();

    // ---------------- Mamba ----------------
    for (int i = tid; i < LSEQ * 256; i += 256) {
        int l = i >> 8, d = i & 255;
        T0[l * TS + d] = f2b(R[HOPA[l] * RS + d] + P.bp_embed[BPEI[l] * 256 + d]);
    }
    __syncthreads();
    ln17g([&](int l, int d) { return b2f(T0[l * TS + d]); }, T1, P.ssm_ln_g, P.ssm_ln_b);
    __syncthreads();
    // xm = silu(conv(in_proj[:, :512]))
    gemmM<8, 8>(T1, TS, ws + OFF_INPROJ, 64, 0, 32,
        [&](int l, int c, float v) { S0[l * SS + c] = f2b(siluf(v * P.conv_w[c] + P.conv_b[c])); });
    __syncthreads();
    // x_proj (N=24 padded to 32): waves 0-1 only
    if (wv < 2) {
        gemmM<16, 1>(S0, SS, ws + OFF_XPROJ, 2, 0, 2,
            [&](int l, int c, float v) { if (c < 24) Dbl[l * 24 + c] = v; });
    }
    __syncthreads();
    // selective scan: thread owns channels tid, tid+256 (y overwrites xm in S0)
    #pragma unroll
    for (int rep = 0; rep < 2; ++rep) {
        const int d = tid + rep * 256;
        float wdt[16];
        #pragma unroll
        for (int r = 0; r < 16; ++r) wdt[r] = P.dt_proj_w[r * 512 + d];
        const float dtb = P.dt_proj_b[d];
        float Ar[4];
        #pragma unroll
        for (int s = 0; s < 4; ++s) Ar[s] = -expf(P.A_log[d * 4 + s]);
        const float Dpd = P.Dp[d];
        float h0 = 0.f, h1 = 0.f, h2 = 0.f, h3 = 0.f;
        for (int t = 0; t < LSEQ; ++t) {
            float a = dtb;
            #pragma unroll
            for (int r = 0; r < 16; ++r) a += Dbl[t * 24 + r] * wdt[r];
            float dt = softplusf(a);
            float xm = b2f(S0[t * SS + d]);
            float dtxm = dt * xm;
            h0 = expf(dt * Ar[0]) * h0 + dtxm * Dbl[t * 24 + 16];
            h1 = expf(dt * Ar[1]) * h1 + dtxm * Dbl[t * 24 + 17];
            h2 = expf(dt * Ar[2]) * h2 + dtxm * Dbl[t * 24 + 18];
            h3 = expf(dt * Ar[3]) * h3 + dtxm * Dbl[t * 24 + 19];
            float y = h0 * Dbl[t * 24 + 20] + h1 * Dbl[t * 24 + 21]
                    + h2 * Dbl[t * 24 + 22] + h3 * Dbl[t * 24 + 23];
            y += Dpd * xm;
            S0[t * SS + d] = f2b(y);
        }
    }
    __syncthreads();
    // z half of in_proj; gate y in place (z never materialized)
    gemmM<8, 8>(T1, TS, ws + OFF_INPROJ, 64, 32, 32,
        [&](int l, int c, float v) {
            float y = b2f(S0[l * SS + c]);
            S0[l * SS + c] = f2b(y * siluf(v));
        });
    __syncthreads();
    gemmM<16, 4>(S0, SS, ws + OFF_OUTPROJ, 16, 0, 16,
        [&](int l, int c, float v) { T0[l * TS + c] = f2b(v); });
    __syncthreads();
    // x_b = 2*x_a + scatter(mamba_out)
    for (int i = tid; i < LSEQ * 256; i += 256) {
        int l = i >> 8, d = i & 255;
        R[l * RS + d] = 2.0f * R[l * RS + d] + b2f(T0[GRAPHA[l] * TS + d]);
    }
    __syncthreads();

    // ---------------- Attention ----------------
    ln17g([&](int l, int d) { return R[l * RS + d]; }, T0, P.ln1_g, P.ln1_b);
    __syncthreads();
    gemmM<8, 4>(T0, TS, ws + OFF_QKV, 48, 0, 16,
        [&](int l, int c, float v) { T1[l * TS + c] = f2b(v); });           // Q
    gemmM<8, 4>(T0, TS, ws + OFF_QKV, 48, 16, 16,
        [&](int l, int c, float v) { S0[l * SS + c] = f2b(v); });           // K
    gemmM<8, 4>(T0, TS, ws + OFF_QKV, 48, 32, 16,
        [&](int l, int c, float v) { S0[l * SS + 256 + c] = f2b(v); });     // V
    __syncthreads();
    {
        const int h = tid >> 5, p = tid & 31;
        for (int idx = p; idx < 289; idx += 32) {
            int i = idx / 17, j = idx - i * 17;
            float s = 0.f;
            #pragma unroll
            for (int d2 = 0; d2 < 32; ++d2)
                s += b2f(T1[i * TS + h * 32 + d2]) * b2f(S0[j * SS + h * 32 + d2]);
            SC[(h * 17 + i) * 17 + j] = f2b(s * 0.17677669529663687f);
        }
    }
    __syncthreads();
    if (tid < 136) {
        u16* row = SC + tid * 17;
        float e[17], mx = -3.0e38f, sum = 0.f;
        #pragma unroll
        for (int j = 0; j < 17; ++j) mx = fmaxf(mx, b2f(row[j]));
        #pragma unroll
        for (int j = 0; j < 17; ++j) { e[j] = expf(b2f(row[j]) - mx); sum += e[j]; }
        float inv = 1.0f / sum;
        #pragma unroll
        for (int j = 0; j < 17; ++j) row[j] = f2b(e[j] * inv);
    }
    __syncthreads();
    {
        const int h = tid >> 5, dd = tid & 31;
        for (int i = 0; i < 17; ++i) {
            float s = 0.f;
            #pragma unroll
            for (int j = 0; j < 17; ++j)
                s += b2f(SC[(h * 17 + i) * 17 + j]) * b2f(S0[j * SS + 256 + h * 32 + dd]);
            T0[i * TS + h * 32 + dd] = f2b(s);  // o (ln1 out is dead)
        }
    }
    __syncthreads();
    // o' = attn_proj(o) + bias  (small magnitude; x1 = R + o' kept implicit)
    gemmM<8, 4>(T0, TS, ws + OFF_ATTNPROJ, 16, 0, 16,
        [&](int l, int c, float v) { T1[l * TS + c] = f2b(v + P.attn_proj_b[c]); });
    __syncthreads();

    // ---------------- MLP + final ----------------
    ln17g([&](int l, int d) { return R[l * RS + d] + b2f(T1[l * TS + d]); },
          T0, P.ln2_g, P.ln2_b);
    __syncthreads();
    {
        f32x4 accO[2][4];
        #pragma unroll
        for (int mt = 0; mt < 2; ++mt)
            #pragma unroll
            for (int i = 0; i < 4; ++i) accO[mt][i] = (f32x4){0.f,0.f,0.f,0.f};
        #pragma unroll
        for (int half = 0; half < 2; ++half) {
            gemmM<8, 8>(T0, TS, ws + OFF_MLP_W1, 64, half * 32, 32,
                [&](int l, int c, float v) {
                    S0[l * SS + c] = f2b(gelu_t(v + P.mlp_b1[half * 512 + c]));
                });
            __syncthreads();
            mfmaAcc<16, 4>(accO, S0, SS, ws + OFF_MLP_W2, 16, 0, 16, half * 16);
            __syncthreads();  // S0 reused next half
        }
        float* outg = P.out + (size_t)b * (LSEQ * 256);
        mfmaStore<4>(accO, 16, [&](int l, int c, float v) {
            outg[l * 256 + c] = v + P.mlp_b2[c] + 2.0f * R[l * RS + c] + b2f(T1[l * TS + c]);
        });
    }
}

extern "C" void kernel_launch(void* const* d_in, const int* in_sizes, int n_in,
                              void* d_out, int out_size, void* d_ws, size_t ws_size,
                              hipStream_t stream) {
    (void)in_sizes; (void)n_in; (void)ws_size; (void)out_size;
    Params P;
    P.x           = (const float*)d_in[0];
    P.gcn_ln_g    = (const float*)d_in[1];
    P.gcn_ln_b    = (const float*)d_in[2];
    P.gcn_w1      = (const float*)d_in[3];
    P.gcn_b1      = (const float*)d_in[4];
    P.gcn_w2      = (const float*)d_in[5];
    P.gcn_b2      = (const float*)d_in[6];
    P.bp_embed    = (const float*)d_in[7];
    P.ssm_ln_g    = (const float*)d_in[8];
    P.ssm_ln_b    = (const float*)d_in[9];
    P.in_proj_w   = (const float*)d_in[10];
    P.conv_w      = (const float*)d_in[11];
    P.conv_b      = (const float*)d_in[12];
    P.x_proj_w    = (const float*)d_in[13];
    P.dt_proj_w   = (const float*)d_in[14];
    P.dt_proj_b   = (const float*)d_in[15];
    P.A_log       = (const float*)d_in[16];
    P.Dp          = (const float*)d_in[17];
    P.out_proj_w  = (const float*)d_in[18];
    P.ln1_g       = (const float*)d_in[19];
    P.ln1_b       = (const float*)d_in[20];
    P.qkv_w       = (const float*)d_in[21];
    P.attn_proj_w = (const float*)d_in[22];
    P.attn_proj_b = (const float*)d_in[23];
    P.ln2_g       = (const float*)d_in[24];
    P.ln2_b       = (const float*)d_in[25];
    P.mlp_w1      = (const float*)d_in[26];
    P.mlp_b1      = (const float*)d_in[27];
    P.mlp_w2      = (const float*)d_in[28];
    P.mlp_b2      = (const float*)d_in[29];
    P.wws         = (const u16*)d_ws;
    P.out         = (float*)d_out;
    hipLaunchKernelGGL(prepack, dim3(712), dim3(256), 0, stream, P);
    hipLaunchKernelGGL(fused_block, dim3(4096), dim3(256), 0, stream, P);
}